// Round 1
// baseline (1618.100 us; speedup 1.0000x reference)
//
#include <hip/hip_runtime.h>

#define N_NODES_DEF 100000
#define K_DIM 32

__device__ __forceinline__ float tanh_fast(float x) {
    // tanh(x) = 1 - 2/(1+e^{2x}); exact at saturation, ~1e-7 abs error
    float e = __expf(2.0f * x);
    return 1.0f - 2.0f / (e + 1.0f);
}

// ---------------- CSR build ----------------

__global__ void k_hist(const int* __restrict__ dst, int* __restrict__ cnt, int n) {
    for (int e = blockIdx.x * blockDim.x + threadIdx.x; e < n; e += gridDim.x * blockDim.x)
        atomicAdd(&cnt[dst[e]], 1);
}

// single-block exclusive scan over n counts -> off[0..n], cur[i]=off[i]
__global__ void k_scan(const int* __restrict__ cnt, int* __restrict__ off,
                       int* __restrict__ cur, int n) {
    __shared__ int sm[1024];
    __shared__ int carry;
    if (threadIdx.x == 0) carry = 0;
    __syncthreads();
    for (int base = 0; base < n; base += 1024) {
        int i = base + (int)threadIdx.x;
        int v = (i < n) ? cnt[i] : 0;
        sm[threadIdx.x] = v;
        __syncthreads();
        #pragma unroll
        for (int d = 1; d < 1024; d <<= 1) {
            int t = ((int)threadIdx.x >= d) ? sm[threadIdx.x - d] : 0;
            __syncthreads();
            sm[threadIdx.x] += t;
            __syncthreads();
        }
        int incl = sm[threadIdx.x];
        int c = carry;
        if (i < n) {
            int excl = c + incl - v;
            off[i] = excl;
            cur[i] = excl;
            if (i == n - 1) off[n] = excl + v;
        }
        __syncthreads();
        if (threadIdx.x == 0) carry = c + sm[1023];
        __syncthreads();
    }
}

__global__ void k_scatter(const int* __restrict__ src, const int* __restrict__ dst,
                          const float* __restrict__ ea, int* __restrict__ cur,
                          int* __restrict__ srcs, float* __restrict__ eas, int n) {
    for (int e = blockIdx.x * blockDim.x + threadIdx.x; e < n; e += gridDim.x * blockDim.x) {
        int d = dst[e];
        int pos = atomicAdd(&cur[d], 1);
        srcs[pos] = src[e];
        eas[pos] = ea[e];
    }
}

// ---------------- per-layer kernels ----------------

// M[n][k] = sum_j h[n][j]*Wx[j][k] + sum_j p[n][j]*Wp[j][k]
template <int ID>
__global__ void k_node_gemm(const float* __restrict__ h, const float* __restrict__ p,
                            const float* __restrict__ Wx, const float* __restrict__ Wp,
                            float* __restrict__ M, int n_nodes) {
    __shared__ float sWx[ID * 32];
    __shared__ float sWp[96];
    for (int i = threadIdx.x; i < ID * 32; i += blockDim.x) sWx[i] = Wx[i];
    if (threadIdx.x < 96) sWp[threadIdx.x] = Wp[threadIdx.x];
    __syncthreads();
    const int grp = threadIdx.x >> 5, k = threadIdx.x & 31, gpb = blockDim.x >> 5;
    int n = blockIdx.x * gpb + grp;
    if (n >= n_nodes) return;
    float hv = (k < ID) ? h[n * ID + k] : 0.0f;
    float pv = (k < 3) ? p[n * 3 + k] : 0.0f;
    float acc = 0.0f;
    #pragma unroll
    for (int j = 0; j < ID; ++j) acc = fmaf(__shfl(hv, j, 32), sWx[j * 32 + k], acc);
    #pragma unroll
    for (int j = 0; j < 3; ++j) acc = fmaf(__shfl(pv, j, 32), sWp[j * 32 + k], acc);
    M[n * 32 + k] = acc;
}

// sim[n][k] = sum over incoming edges e (dst==n) of tanh(M[src_e][k] + cnst_n[k] + ea_e*We[k])
__global__ void k_edge_msg(const float* __restrict__ M, const float* __restrict__ p,
                           const int* __restrict__ off, const int* __restrict__ srcs,
                           const float* __restrict__ eas,
                           const float* __restrict__ Wp, const float* __restrict__ We,
                           const float* __restrict__ b,
                           float* __restrict__ sim, int n_nodes) {
    __shared__ float sWp[96];
    __shared__ float sWe[32];
    __shared__ float sB[32];
    if (threadIdx.x < 96) sWp[threadIdx.x] = Wp[threadIdx.x];
    if (threadIdx.x < 32) { sWe[threadIdx.x] = We[threadIdx.x]; sB[threadIdx.x] = b[threadIdx.x]; }
    __syncthreads();
    const int grp = threadIdx.x >> 5, k = threadIdx.x & 31, gpb = blockDim.x >> 5;
    int n = blockIdx.x * gpb + grp;
    if (n >= n_nodes) return;
    float pn = (k < 3) ? p[n * 3 + k] : 0.0f;
    float pn0 = __shfl(pn, 0, 32), pn1 = __shfl(pn, 1, 32), pn2 = __shfl(pn, 2, 32);
    float cnst = sB[k] - (pn0 * sWp[k] + pn1 * sWp[32 + k] + pn2 * sWp[64 + k]);
    float we = sWe[k];
    float acc = 0.0f;
    int e1 = off[n + 1];
    for (int e = off[n]; e < e1; ++e) {
        int s = srcs[e];
        float ea = eas[e];
        float pre = fmaf(ea, we, cnst) + M[s * 32 + k];
        acc += tanh_fast(pre);
    }
    sim[n * 32 + k] = acc;
}

// hout[n][k] = sum over incoming edges e (dst==n) of sim[src_e][k]
__global__ void k_prop(const float* __restrict__ sim, const int* __restrict__ off,
                       const int* __restrict__ srcs, float* __restrict__ hout, int n_nodes) {
    const int grp = threadIdx.x >> 5, k = threadIdx.x & 31, gpb = blockDim.x >> 5;
    int n = blockIdx.x * gpb + grp;
    if (n >= n_nodes) return;
    float acc = 0.0f;
    int e1 = off[n + 1];
    for (int e = off[n]; e < e1; ++e) acc += sim[srcs[e] * 32 + k];
    hout[n * 32 + k] = acc;
}

// ---------------- pooling + head ----------------

__global__ void k_pool(const float* __restrict__ h, const int* __restrict__ batch,
                       const float* __restrict__ Wh, const float* __restrict__ bh,
                       float* __restrict__ out, int n_nodes, int n_graphs) {
    __shared__ int sLo, sHi;
    __shared__ float red[256];
    int g = blockIdx.x;
    if (threadIdx.x == 0) {
        int lo = 0, hi = n_nodes;
        while (lo < hi) { int m = (lo + hi) >> 1; if (batch[m] < g) lo = m + 1; else hi = m; }
        sLo = lo;
        lo = 0; hi = n_nodes; int g1 = g + 1;
        while (lo < hi) { int m = (lo + hi) >> 1; if (batch[m] < g1) lo = m + 1; else hi = m; }
        sHi = lo;
    }
    __syncthreads();
    int lo = sLo, hi = sHi;
    int k = threadIdx.x & 31, r = threadIdx.x >> 5;
    float acc = 0.0f;
    for (int n = lo + r; n < hi; n += 8) acc += h[n * 32 + k];
    red[threadIdx.x] = acc;
    __syncthreads();
    if (threadIdx.x < 32) {
        float s = 0.0f;
        #pragma unroll
        for (int r2 = 0; r2 < 8; ++r2) s += red[r2 * 32 + k];
        float c = (float)(hi - lo);
        float rep = s / fmaxf(c, 1.0f);
        out[n_graphs + g * 32 + k] = rep;          // graph_rep
        float t = rep * Wh[k];
        #pragma unroll
        for (int d = 16; d > 0; d >>= 1) t += __shfl_down(t, d, 32);
        if (k == 0) out[g] = t + bh[0];            // pred
    }
}

// ---------------- launch ----------------

extern "C" void kernel_launch(void* const* d_in, const int* in_sizes, int n_in,
                              void* d_out, int out_size, void* d_ws, size_t ws_size,
                              hipStream_t stream) {
    const float* x   = (const float*)d_in[0];   // [N,5]
    const float* p   = (const float*)d_in[1];   // [N,3]
    const float* ea  = (const float*)d_in[2];   // [E,1]
    const float* Wx0 = (const float*)d_in[3];
    const float* Wx1 = (const float*)d_in[4];
    const float* Wx2 = (const float*)d_in[5];
    const float* Wp0 = (const float*)d_in[6];
    const float* Wp1 = (const float*)d_in[7];
    const float* Wp2 = (const float*)d_in[8];
    const float* We0 = (const float*)d_in[9];
    const float* We1 = (const float*)d_in[10];
    const float* We2 = (const float*)d_in[11];
    const float* b0  = (const float*)d_in[12];
    const float* b1  = (const float*)d_in[13];
    const float* b2  = (const float*)d_in[14];
    const float* Wh  = (const float*)d_in[15];
    const float* bh  = (const float*)d_in[16];
    const int* edge_index = (const int*)d_in[17]; // [2,E]
    const int* batch      = (const int*)d_in[18]; // [N]

    const int N = in_sizes[0] / 5;
    const int E = in_sizes[17] / 2;
    const int G = out_size / 33;                  // G*(1+K), K=32

    const int* srcp = edge_index;
    const int* dstp = edge_index + E;

    // workspace carve (256B aligned)
    char* w = (char*)d_ws;
    auto alloc = [&](size_t bytes) -> void* {
        void* r = (void*)w;
        w += (bytes + 255) & ~(size_t)255;
        return r;
    };
    int*   cnt  = (int*)alloc((size_t)N * 4);
    int*   off  = (int*)alloc((size_t)(N + 1) * 4);
    int*   cur  = (int*)alloc((size_t)N * 4);
    int*   srcs = (int*)alloc((size_t)E * 4);
    float* eas  = (float*)alloc((size_t)E * 4);
    float* M    = (float*)alloc((size_t)N * K_DIM * 4);
    float* hA   = (float*)alloc((size_t)N * K_DIM * 4);
    float* hB   = (float*)alloc((size_t)N * K_DIM * 4);

    const int NB = (N + 7) / 8;   // 8 node-groups (32 lanes each) per 256-thread block

    // CSR by dst (rebuilt every call: deterministic inputs -> same structure)
    hipMemsetAsync(cnt, 0, (size_t)N * 4, stream);
    k_hist<<<2048, 256, 0, stream>>>(dstp, cnt, E);
    k_scan<<<1, 1024, 0, stream>>>(cnt, off, cur, N);
    k_scatter<<<2048, 256, 0, stream>>>(srcp, dstp, ea, cur, srcs, eas, E);

    // layer 0 (h = x, ID=5)
    k_node_gemm<5><<<NB, 256, 0, stream>>>(x, p, Wx0, Wp0, M, N);
    k_edge_msg<<<NB, 256, 0, stream>>>(M, p, off, srcs, eas, Wp0, We0, b0, hA, N);
    k_prop<<<NB, 256, 0, stream>>>(hA, off, srcs, hB, N);
    // layer 1
    k_node_gemm<32><<<NB, 256, 0, stream>>>(hB, p, Wx1, Wp1, M, N);
    k_edge_msg<<<NB, 256, 0, stream>>>(M, p, off, srcs, eas, Wp1, We1, b1, hA, N);
    k_prop<<<NB, 256, 0, stream>>>(hA, off, srcs, hB, N);
    // layer 2
    k_node_gemm<32><<<NB, 256, 0, stream>>>(hB, p, Wx2, Wp2, M, N);
    k_edge_msg<<<NB, 256, 0, stream>>>(M, p, off, srcs, eas, Wp2, We2, b2, hA, N);
    k_prop<<<NB, 256, 0, stream>>>(hA, off, srcs, hB, N);

    // pool + head
    k_pool<<<G, 256, 0, stream>>>(hB, batch, Wh, bh, (float*)d_out, N, G);
}

// Round 2
// 1168.667 us; speedup vs baseline: 1.3846x; 1.3846x over previous
//
#include <hip/hip_runtime.h>

#define K_DIM 32

__device__ __forceinline__ float tanh_fast(float x) {
    float e = __expf(2.0f * x);
    return 1.0f - 2.0f / (e + 1.0f);
}

// ---------------- CSR build ----------------

__global__ void k_hist(const int* __restrict__ dst, int* __restrict__ cnt, int n) {
    for (int e = blockIdx.x * blockDim.x + threadIdx.x; e < n; e += gridDim.x * blockDim.x)
        atomicAdd(&cnt[dst[e]], 1);
}

// phase 1: per-1024-tile sums (grid = n_pad/1024, block = 256, int4 loads)
__global__ void k_scan_part(const int* __restrict__ cnt, int* __restrict__ part) {
    __shared__ int sm[256];
    int t = threadIdx.x;
    int g = blockIdx.x * 1024 + t * 4;
    const int4 v = *(const int4*)(cnt + g);
    sm[t] = v.x + v.y + v.z + v.w;
    __syncthreads();
    #pragma unroll
    for (int d = 128; d > 0; d >>= 1) {
        if (t < d) sm[t] += sm[t + d];
        __syncthreads();
    }
    if (t == 0) part[blockIdx.x] = sm[0];
}

// phase 2: single-block inclusive scan of tile sums (nblk <= 128)
__global__ void k_scan_top(int* __restrict__ part, int nblk,
                           int* __restrict__ off, int n, int total) {
    __shared__ int sm[128];
    int t = threadIdx.x;
    sm[t] = (t < nblk) ? part[t] : 0;
    __syncthreads();
    #pragma unroll
    for (int d = 1; d < 128; d <<= 1) {
        int v = (t >= d) ? sm[t - d] : 0;
        __syncthreads();
        sm[t] += v;
        __syncthreads();
    }
    if (t < nblk) part[t] = sm[t];   // inclusive
    if (t == 0) off[n] = total;
}

// phase 3: rescan each tile, add carry, emit off & cur
__global__ void k_scan_apply(const int* __restrict__ cnt, const int* __restrict__ part,
                             int* __restrict__ off, int* __restrict__ cur, int n) {
    __shared__ int sm[256];
    int t = threadIdx.x;
    int g = blockIdx.x * 1024 + t * 4;
    const int4 v = *(const int4*)(cnt + g);
    int s0 = v.x, s1 = s0 + v.y, s2 = s1 + v.z, s3 = s2 + v.w;
    sm[t] = s3;
    __syncthreads();
    #pragma unroll
    for (int d = 1; d < 256; d <<= 1) {
        int tv = (t >= d) ? sm[t - d] : 0;
        __syncthreads();
        sm[t] += tv;
        __syncthreads();
    }
    int carry = blockIdx.x ? part[blockIdx.x - 1] : 0;
    int excl = (t ? sm[t - 1] : 0) + carry;
    if (g + 3 < n) {
        int4 o = make_int4(excl, excl + s0, excl + s1, excl + s2);
        *(int4*)(off + g) = o;
        *(int4*)(cur + g) = o;
    } else {
        int pre[4] = {0, s0, s1, s2};
        #pragma unroll
        for (int j = 0; j < 4; ++j)
            if (g + j < n) { off[g + j] = excl + pre[j]; cur[g + j] = excl + pre[j]; }
    }
}

// scatter: one packed 8B store per edge (src idx, ea bits)
__global__ void k_scatter(const int* __restrict__ src, const int* __restrict__ dst,
                          const float* __restrict__ ea, int* __restrict__ cur,
                          uint2* __restrict__ packed, int n) {
    for (int e = blockIdx.x * blockDim.x + threadIdx.x; e < n; e += gridDim.x * blockDim.x) {
        int d = dst[e];
        int pos = atomicAdd(&cur[d], 1);
        packed[pos] = make_uint2((unsigned)src[e], __float_as_uint(ea[e]));
    }
}

// ---------------- per-layer kernels ----------------

// layer-0 GEMM: M = x@Wx0 + p@Wp0  (input dim 5)
__global__ void k_node_gemm5(const float* __restrict__ h, const float* __restrict__ p,
                             const float* __restrict__ Wx, const float* __restrict__ Wp,
                             float* __restrict__ M, int n_nodes) {
    __shared__ float sWx[5 * 32];
    __shared__ float sWp[96];
    for (int i = threadIdx.x; i < 5 * 32; i += blockDim.x) sWx[i] = Wx[i];
    if (threadIdx.x < 96) sWp[threadIdx.x] = Wp[threadIdx.x];
    __syncthreads();
    const int k = threadIdx.x & 31;
    int n = blockIdx.x * (blockDim.x >> 5) + (threadIdx.x >> 5);
    if (n >= n_nodes) return;
    float hv = (k < 5) ? h[n * 5 + k] : 0.0f;
    float pv = (k < 3) ? p[n * 3 + k] : 0.0f;
    float acc = 0.0f;
    #pragma unroll
    for (int j = 0; j < 5; ++j) acc = fmaf(__shfl(hv, j, 32), sWx[j * 32 + k], acc);
    #pragma unroll
    for (int j = 0; j < 3; ++j) acc = fmaf(__shfl(pv, j, 32), sWp[j * 32 + k], acc);
    M[n * 32 + k] = acc;
}

// sim[n][k] = sum_{e: dst==n} tanh(M[src_e][k] + cnst_n[k] + ea_e*We[k])
__global__ void k_edge_msg(const float* __restrict__ M, const float* __restrict__ p,
                           const int* __restrict__ off, const uint2* __restrict__ packed,
                           const float* __restrict__ Wp, const float* __restrict__ We,
                           const float* __restrict__ b,
                           float* __restrict__ sim, int n_nodes) {
    __shared__ float sWp[96];
    __shared__ float sWe[32];
    __shared__ float sB[32];
    if (threadIdx.x < 96) sWp[threadIdx.x] = Wp[threadIdx.x];
    if (threadIdx.x < 32) { sWe[threadIdx.x] = We[threadIdx.x]; sB[threadIdx.x] = b[threadIdx.x]; }
    __syncthreads();
    const int k = threadIdx.x & 31;
    int n = blockIdx.x * (blockDim.x >> 5) + (threadIdx.x >> 5);
    if (n >= n_nodes) return;
    float pn = (k < 3) ? p[n * 3 + k] : 0.0f;
    float cnst = sB[k] - (__shfl(pn, 0, 32) * sWp[k] + __shfl(pn, 1, 32) * sWp[32 + k]
                          + __shfl(pn, 2, 32) * sWp[64 + k]);
    float we = sWe[k];
    float acc = 0.0f;
    int e0 = off[n], e1 = off[n + 1];
    for (int base = e0; base < e1; base += 32) {
        uint2 pk = (base + k < e1) ? packed[base + k] : make_uint2(0u, 0u);
        int m = min(32, e1 - base);
        for (int j = 0; j < m; ++j) {
            int s = (int)__shfl(pk.x, j, 32);
            float eav = __uint_as_float(__shfl(pk.y, j, 32));
            acc += tanh_fast(fmaf(eav, we, cnst) + M[s * 32 + k]);
        }
    }
    sim[n * 32 + k] = acc;
}

// h_next[n] = sum_{e: dst==n} sim[src_e]; optionally fused with next-layer GEMM
template <int FUSE>
__global__ void k_prop_gemm(const float* __restrict__ sim, const int* __restrict__ off,
                            const uint2* __restrict__ packed, const float* __restrict__ p,
                            const float* __restrict__ Wx, const float* __restrict__ Wp,
                            float* __restrict__ outM, int n_nodes) {
    __shared__ float sWx[1024];
    __shared__ float sWp[96];
    if (FUSE) {
        for (int i = threadIdx.x; i < 1024; i += blockDim.x) sWx[i] = Wx[i];
        if (threadIdx.x < 96) sWp[threadIdx.x] = Wp[threadIdx.x];
        __syncthreads();
    }
    const int k = threadIdx.x & 31;
    int n = blockIdx.x * (blockDim.x >> 5) + (threadIdx.x >> 5);
    if (n >= n_nodes) return;
    float acc = 0.0f;
    int e0 = off[n], e1 = off[n + 1];
    for (int base = e0; base < e1; base += 32) {
        unsigned sv = (base + k < e1) ? packed[base + k].x : 0u;
        int m = min(32, e1 - base);
        for (int j = 0; j < m; ++j) {
            int s = (int)__shfl(sv, j, 32);
            acc += sim[s * 32 + k];
        }
    }
    if (!FUSE) { outM[n * 32 + k] = acc; return; }
    float mm = 0.0f;
    #pragma unroll
    for (int j = 0; j < 32; ++j) mm = fmaf(__shfl(acc, j, 32), sWx[j * 32 + k], mm);
    float pv = (k < 3) ? p[n * 3 + k] : 0.0f;
    mm = fmaf(__shfl(pv, 0, 32), sWp[k], mm);
    mm = fmaf(__shfl(pv, 1, 32), sWp[32 + k], mm);
    mm = fmaf(__shfl(pv, 2, 32), sWp[64 + k], mm);
    outM[n * 32 + k] = mm;
}

// ---------------- pooling + head ----------------

__global__ void k_pool(const float* __restrict__ h, const int* __restrict__ batch,
                       const float* __restrict__ Wh, const float* __restrict__ bh,
                       float* __restrict__ out, int n_nodes, int n_graphs) {
    __shared__ int sLo, sHi;
    __shared__ float red[256];
    int g = blockIdx.x;
    if (threadIdx.x == 0) {
        int lo = 0, hi = n_nodes;
        while (lo < hi) { int m = (lo + hi) >> 1; if (batch[m] < g) lo = m + 1; else hi = m; }
        sLo = lo;
        lo = 0; hi = n_nodes; int g1 = g + 1;
        while (lo < hi) { int m = (lo + hi) >> 1; if (batch[m] < g1) lo = m + 1; else hi = m; }
        sHi = lo;
    }
    __syncthreads();
    int lo = sLo, hi = sHi;
    int k = threadIdx.x & 31, r = threadIdx.x >> 5;
    float acc = 0.0f;
    for (int n = lo + r; n < hi; n += 8) acc += h[n * 32 + k];
    red[threadIdx.x] = acc;
    __syncthreads();
    if (threadIdx.x < 32) {
        float s = 0.0f;
        #pragma unroll
        for (int r2 = 0; r2 < 8; ++r2) s += red[r2 * 32 + k];
        float c = (float)(hi - lo);
        float rep = s / fmaxf(c, 1.0f);
        out[n_graphs + g * 32 + k] = rep;
        float t = rep * Wh[k];
        #pragma unroll
        for (int d = 16; d > 0; d >>= 1) t += __shfl_down(t, d, 32);
        if (k == 0) out[g] = t + bh[0];
    }
}

// ---------------- launch ----------------

extern "C" void kernel_launch(void* const* d_in, const int* in_sizes, int n_in,
                              void* d_out, int out_size, void* d_ws, size_t ws_size,
                              hipStream_t stream) {
    const float* x   = (const float*)d_in[0];
    const float* p   = (const float*)d_in[1];
    const float* ea  = (const float*)d_in[2];
    const float* Wx0 = (const float*)d_in[3];
    const float* Wx1 = (const float*)d_in[4];
    const float* Wx2 = (const float*)d_in[5];
    const float* Wp0 = (const float*)d_in[6];
    const float* Wp1 = (const float*)d_in[7];
    const float* Wp2 = (const float*)d_in[8];
    const float* We0 = (const float*)d_in[9];
    const float* We1 = (const float*)d_in[10];
    const float* We2 = (const float*)d_in[11];
    const float* b0  = (const float*)d_in[12];
    const float* b1  = (const float*)d_in[13];
    const float* b2  = (const float*)d_in[14];
    const float* Wh  = (const float*)d_in[15];
    const float* bh  = (const float*)d_in[16];
    const int* edge_index = (const int*)d_in[17];
    const int* batch      = (const int*)d_in[18];

    const int N = in_sizes[0] / 5;
    const int E = in_sizes[17] / 2;
    const int G = out_size / 33;

    const int NP = (N + 1023) & ~1023;      // padded to 1024
    const int NTILE = NP / 1024;            // scan tiles

    const int* srcp = edge_index;
    const int* dstp = edge_index + E;

    char* w = (char*)d_ws;
    auto alloc = [&](size_t bytes) -> void* {
        void* r = (void*)w;
        w += (bytes + 255) & ~(size_t)255;
        return r;
    };
    int*   cnt    = (int*)alloc((size_t)NP * 4);
    int*   off    = (int*)alloc((size_t)(N + 1) * 4);
    int*   cur    = (int*)alloc((size_t)N * 4);
    int*   part   = (int*)alloc((size_t)NTILE * 4);
    uint2* packed = (uint2*)alloc((size_t)E * 8);
    float* M      = (float*)alloc((size_t)N * K_DIM * 4);
    float* hA     = (float*)alloc((size_t)N * K_DIM * 4);
    float* hB     = (float*)alloc((size_t)N * K_DIM * 4);

    const int NB = (N + 7) / 8;

    // CSR by dst
    hipMemsetAsync(cnt, 0, (size_t)NP * 4, stream);
    k_hist<<<2048, 256, 0, stream>>>(dstp, cnt, E);
    k_scan_part<<<NTILE, 256, 0, stream>>>(cnt, part);
    k_scan_top<<<1, 128, 0, stream>>>(part, NTILE, off, N, E);
    k_scan_apply<<<NTILE, 256, 0, stream>>>(cnt, part, off, cur, N);
    k_scatter<<<2048, 256, 0, stream>>>(srcp, dstp, ea, cur, packed, E);

    // layer 0
    k_node_gemm5<<<NB, 256, 0, stream>>>(x, p, Wx0, Wp0, M, N);
    k_edge_msg<<<NB, 256, 0, stream>>>(M, p, off, packed, Wp0, We0, b0, hA, N);
    k_prop_gemm<1><<<NB, 256, 0, stream>>>(hA, off, packed, p, Wx1, Wp1, M, N);
    // layer 1
    k_edge_msg<<<NB, 256, 0, stream>>>(M, p, off, packed, Wp1, We1, b1, hA, N);
    k_prop_gemm<1><<<NB, 256, 0, stream>>>(hA, off, packed, p, Wx2, Wp2, M, N);
    // layer 2
    k_edge_msg<<<NB, 256, 0, stream>>>(M, p, off, packed, Wp2, We2, b2, hA, N);
    k_prop_gemm<0><<<NB, 256, 0, stream>>>(hA, off, packed, p, nullptr, nullptr, hB, N);

    // pool + head
    k_pool<<<G, 256, 0, stream>>>(hB, batch, Wh, bh, (float*)d_out, N, G);
}